// Round 2
// baseline (224.548 us; speedup 1.0000x reference)
//
#include <hip/hip_runtime.h>
#include <hip/hip_bf16.h>

#define C_IN  64
#define C_OUT 128
#define KK    27
#define HH    100000
#define TB    1563         // transpose blocks = ceil(HH/64)
#define WB    108          // weight-convert blocks (108*2048 = 221184 elems)
#define NBLK  391          // ceil(HH/256)

typedef __attribute__((ext_vector_type(8))) short s8v;    // 8 bf16 (MFMA A/B frag)
typedef __attribute__((ext_vector_type(4))) float f32x4;  // MFMA C/D frag

__device__ inline unsigned short f2bf(float f) {
    __hip_bfloat16 h = __float2bfloat16(f);
    return *reinterpret_cast<unsigned short*>(&h);
}

__device__ inline void dma16(const void* g, void* l) {
    __builtin_amdgcn_global_load_lds((const __attribute__((address_space(1))) void*)g,
                                     (__attribute__((address_space(3))) void*)l, 16, 0, 0);
}

// ---- prep: transpose x -> xt (bf16, [h][64] plain), W -> wk (bf16, [k][o][64] XOR-swizzled) ----
// wk physical chunk pj (16B unit) holds logical chunk pj ^ (o&7).
__global__ __launch_bounds__(256) void prep_kernel(const float* __restrict__ x,
                                                   const float* __restrict__ w,
                                                   unsigned short* __restrict__ xt,
                                                   unsigned short* __restrict__ wk) {
    const int tid = threadIdx.x;
    if (blockIdx.x < TB) {
        __shared__ __align__(16) unsigned short ts[64 * 72];
        const int hbase = blockIdx.x * 64;
        #pragma unroll
        for (int it = 0; it < 16; ++it) {
            int i = it * 256 + tid;           // 64h x 64c
            int c = i >> 6, hl = i & 63;
            int hg = hbase + hl;
            float v = (hg < HH) ? x[(size_t)c * HH + hg] : 0.f;  // coalesced in h
            ts[hl * 72 + c] = f2bf(v);
        }
        __syncthreads();
        #pragma unroll
        for (int it = 0; it < 2; ++it) {
            int u = it * 256 + tid;           // 64 rows x 8 chunks of 16B
            int hl = u >> 3, part = u & 7;
            int hg = hbase + hl;
            if (hg < HH)
                *(int4*)&xt[(size_t)hg * 64 + part * 8] = *(const int4*)&ts[hl * 72 + part * 8];
        }
    } else {
        int b = blockIdx.x - TB;
        int base = b * 2048 + tid;
        #pragma unroll
        for (int j = 0; j < 8; ++j) {
            int t = base + j * 256;           // wk index: t = k*8192 + o*64 + jj
            int jj = t & 63, o = (t >> 6) & 127, kx = t >> 13;
            int lc = (jj >> 3) ^ (o & 7);     // logical chunk
            int c  = lc * 8 + (jj & 7);
            wk[t] = f2bf(w[(size_t)o * (C_IN * KK) + c * KK + kx]);
        }
    }
}

// ---------------- main gather-GEMM ----------------
// block 256 thr = 4 waves; tile M=128 (all o) x N=256 h; wave w: h strip [w*64, w*64+64)
// A (weights) async-DMA double-buffered in LDS; B (gathered cols) direct global->VGPR,
// 1-iteration prefetch kept IN FLIGHT across the barrier via counted vmcnt + raw s_barrier
// (T4). Per-wave vmcnt ledger, steady state:
//   enter iter: 8 outstanding (cur gathers)
//   +4 W-DMA, +8 nxt gathers  -> 20
//   s_waitcnt vmcnt(12)        -> cur landed; 12 newest (4 DMA + 8 gathers) in flight
//   MFMA phase (ds_read A + mfma)
//   s_waitcnt vmcnt(8) lgkmcnt(0) -> own DMAs landed + LDS reads done; gathers stay out
//   s_barrier                  -> all waves' DMAs for k+1 visible; W dbuf race-free
__global__ __launch_bounds__(256, 2) void conv_main(const unsigned short* __restrict__ xt,
                                                    const unsigned short* __restrict__ wk,
                                                    const int* __restrict__ neigh,
                                                    float* __restrict__ out) {
    __shared__ int neigh_s[256 * KK];                            // 27648 B, [h][k]
    __shared__ __align__(16) unsigned short w_s[2][128 * 64];    // 2 x 16 KB, XOR-swizzled rows

    const int tid  = threadIdx.x;
    const int wave = tid >> 6;
    const int lane = tid & 63;
    const int col  = lane & 15;
    const int quad = lane >> 4;
    const int hbase = blockIdx.x * 256;

    // ---- issue W DMA for k=0 into buf 0 (overlaps neigh staging) ----
    #pragma unroll
    for (int i = 0; i < 4; ++i) {
        int row_base = wave * 8 + i * 32; // 8 rows = 1024 B per inst
        dma16(wk + row_base * 64 + lane * 8, &w_s[0][row_base * 64]);
    }

    // ---- stage neighbor indices (coalesced) ----
    #pragma unroll
    for (int j = 0; j < KK; ++j) {
        int i = j * 256 + tid;                // 6912 = 27*256 exactly
        int hl = i / KK, kx = i - hl * KK;
        int hg = hbase + hl;
        neigh_s[i] = (hg < HH) ? neigh[(size_t)hg * KK + kx] : -1;
    }

    f32x4 acc[8][4];
    #pragma unroll
    for (int mt = 0; mt < 8; ++mt)
        #pragma unroll
        for (int nt = 0; nt < 4; ++nt)
            acc[mt][nt] = (f32x4){0.f, 0.f, 0.f, 0.f};

    __syncthreads();   // neigh_s ready; full drain (DMA k=0 done); vmcnt = 0 here

    // ---- B-fragment loader: 8 x 16B direct gathers into VGPRs ----
    int4 cur[2][4], nxt[2][4];
    const int pc_b = (quad * 8);              // element offset of quad's chunk within column
    auto loadB = [&](int kk, int4 (&frag)[2][4]) {
        #pragma unroll
        for (int nt = 0; nt < 4; ++nt) {
            int n = wave * 64 + nt * 16 + col;
            int idx = neigh_s[n * KK + kk];
            if (idx >= 0) {
                const unsigned short* base = xt + (size_t)idx * 64 + pc_b;
                frag[0][nt] = *(const int4*)(base);
                frag[1][nt] = *(const int4*)(base + 32);
            } else {
                frag[0][nt] = make_int4(0, 0, 0, 0);
                frag[1][nt] = make_int4(0, 0, 0, 0);
            }
        }
    };

    loadB(0, cur);     // 8 gathers in flight entering the loop

    int p = 0;
    #pragma unroll 1
    for (int k = 0; k < KK; ++k) {
        if (k + 1 < KK) {
            // async W DMA for k+1 into other buffer (safe: all reads of that buffer
            // were lgkmcnt(0)-drained before the barrier that ended iter k-1)
            const unsigned short* src = wk + (size_t)(k + 1) * (C_OUT * C_IN);
            #pragma unroll
            for (int i = 0; i < 4; ++i) {
                int row_base = wave * 8 + i * 32;
                dma16(src + row_base * 64 + lane * 8, &w_s[p ^ 1][row_base * 64]);
            }
            loadB(k + 1, nxt);   // issue next gathers; land one full iteration later
            asm volatile("s_waitcnt vmcnt(12)" ::: "memory");  // cur gathers landed
        } else {
            asm volatile("s_waitcnt vmcnt(0)" ::: "memory");   // final iter: drain all
        }
        __builtin_amdgcn_sched_barrier(0);

        // MFMA phase on w_s[p] + cur
        #pragma unroll
        for (int ch = 0; ch < 2; ++ch) {
            const int pc = (ch * 4 + quad) ^ (col & 7);   // physical chunk (XOR swizzle)
            #pragma unroll
            for (int mt = 0; mt < 8; ++mt) {
                s8v a = *(const s8v*)&w_s[p][(mt * 16 + col) * 64 + pc * 8];
                #pragma unroll
                for (int nt = 0; nt < 4; ++nt) {
                    s8v b = __builtin_bit_cast(s8v, cur[ch][nt]);
                    acc[mt][nt] = __builtin_amdgcn_mfma_f32_16x16x32_bf16(a, b, acc[mt][nt], 0, 0, 0);
                }
            }
        }

        if (k + 1 < KK) {
            // drain own 4 W-DMAs (keep 8 gathers in flight) + finish LDS reads, then barrier
            asm volatile("s_waitcnt vmcnt(8) lgkmcnt(0)" ::: "memory");
            __builtin_amdgcn_s_barrier();
            __builtin_amdgcn_sched_barrier(0);
            #pragma unroll
            for (int ch = 0; ch < 2; ++ch)
                #pragma unroll
                for (int nt = 0; nt < 4; ++nt)
                    cur[ch][nt] = nxt[ch][nt];
            p ^= 1;
        }
    }

    // ---- epilogue: D row = quad*4+r (o), col = lane&15 (h); relu + fp32 store ----
    #pragma unroll
    for (int mt = 0; mt < 8; ++mt) {
        #pragma unroll
        for (int nt = 0; nt < 4; ++nt) {
            int hg = hbase + wave * 64 + nt * 16 + col;
            if (hg < HH) {
                #pragma unroll
                for (int r = 0; r < 4; ++r) {
                    int o = mt * 16 + quad * 4 + r;
                    float v = acc[mt][nt][r];
                    out[(size_t)o * HH + hg] = v > 0.f ? v : 0.f;
                }
            }
        }
    }
}

extern "C" void kernel_launch(void* const* d_in, const int* in_sizes, int n_in,
                              void* d_out, int out_size, void* d_ws, size_t ws_size,
                              hipStream_t stream) {
    const float* data_in = (const float*)d_in[0];
    const int*   neigh   = (const int*)d_in[1];
    const float* weight  = (const float*)d_in[2];
    float* out = (float*)d_out;

    unsigned short* xt = (unsigned short*)d_ws;            // H*64 bf16 = 12.8 MB
    unsigned short* wk = xt + (size_t)HH * 64;             // 27*128*64 bf16 = 442 KB

    prep_kernel<<<TB + WB, 256, 0, stream>>>(data_in, weight, xt, wk);
    conv_main<<<NBLK, 256, 0, stream>>>(xt, wk, neigh, out);
}

// Round 3
// 168.370 us; speedup vs baseline: 1.3337x; 1.3337x over previous
//
#include <hip/hip_runtime.h>
#include <hip/hip_bf16.h>

#define C_IN  64
#define C_OUT 128
#define KK    27
#define HH    100000
#define TB    1563         // transpose blocks = ceil(HH/64)
#define WB    108          // weight-convert blocks (108*2048 = 221184 elems)
#define NBLK  391          // ceil(HH/256)

typedef __attribute__((ext_vector_type(8))) short s8v;    // 8 bf16 (MFMA A/B frag)
typedef __attribute__((ext_vector_type(4))) float f32x4;  // MFMA C/D frag

__device__ inline unsigned short f2bf(float f) {
    __hip_bfloat16 h = __float2bfloat16(f);
    return *reinterpret_cast<unsigned short*>(&h);
}

__device__ inline void dma16(const void* g, void* l) {
    __builtin_amdgcn_global_load_lds((const __attribute__((address_space(1))) void*)g,
                                     (__attribute__((address_space(3))) void*)l, 16, 0, 0);
}

// ---- prep: transpose x -> xt (bf16, [h][64] plain, + zeroed shadow row at h=HH),
//      W -> wk (bf16, [k][o][64] XOR-swizzled: phys chunk pj holds logical pj^(o&7)) ----
__global__ __launch_bounds__(256) void prep_kernel(const float* __restrict__ x,
                                                   const float* __restrict__ w,
                                                   unsigned short* __restrict__ xt,
                                                   unsigned short* __restrict__ wk) {
    const int tid = threadIdx.x;
    if (blockIdx.x < TB) {
        __shared__ __align__(16) unsigned short ts[64 * 72];
        const int hbase = blockIdx.x * 64;
        #pragma unroll
        for (int it = 0; it < 16; ++it) {
            int i = it * 256 + tid;           // 64h x 64c
            int c = i >> 6, hl = i & 63;
            int hg = hbase + hl;
            float v = (hg < HH) ? x[(size_t)c * HH + hg] : 0.f;  // coalesced in h
            ts[hl * 72 + c] = f2bf(v);
        }
        __syncthreads();
        #pragma unroll
        for (int it = 0; it < 2; ++it) {
            int u = it * 256 + tid;           // 64 rows x 8 chunks of 16B
            int hl = u >> 3, part = u & 7;
            int hg = hbase + hl;
            if (hg < HH)
                *(int4*)&xt[(size_t)hg * 64 + part * 8] = *(const int4*)&ts[hl * 72 + part * 8];
        }
    } else {
        int b = blockIdx.x - TB;
        // zeroed shadow rows HH..HH+7 (gather target for OOB/negative neigh indices)
        if (b == 0 && tid < 64)
            *(int4*)&xt[(size_t)HH * 64 + tid * 8] = make_int4(0, 0, 0, 0);
        int base = b * 2048 + tid;
        #pragma unroll
        for (int j = 0; j < 8; ++j) {
            int t = base + j * 256;           // wk index: t = k*8192 + o*64 + jj
            int jj = t & 63, o = (t >> 6) & 127, kx = t >> 13;
            int lc = (jj >> 3) ^ (o & 7);     // logical chunk
            int c  = lc * 8 + (jj & 7);
            wk[t] = f2bf(w[(size_t)o * (C_IN * KK) + c * KK + kx]);
        }
    }
}

// ---------------- main gather-GEMM ----------------
// block 256 thr = 4 waves; tile M=128 (all o) x N=256 h; wave w: h strip [w*64, w*64+64)
// A (weights) async-DMA double-buffered LDS; B (gathered cols) direct global->VGPR with
// 1-iter prefetch that STAYS IN FLIGHT across the barrier:
//   - raw s_barrier, preceded only by s_waitcnt vmcnt(8) lgkmcnt(0)
//   - no cur=nxt copies: 2x-unrolled loop with swapped buffer names
//   - gathers UNCONDITIONAL (exact vmcnt ledger): neg/OOB idx clamps to zero row HH
__global__ __launch_bounds__(256, 2) void conv_main(const unsigned short* __restrict__ xt,
                                                    const unsigned short* __restrict__ wk,
                                                    const int* __restrict__ neigh,
                                                    float* __restrict__ out) {
    __shared__ int neigh_s[256 * KK];                            // 27648 B, [h][k]
    __shared__ __align__(16) unsigned short w_s[2][128 * 64];    // 2 x 16 KB, XOR-swizzled rows

    const int tid  = threadIdx.x;
    const int wave = tid >> 6;
    const int lane = tid & 63;
    const int col  = lane & 15;
    const int quad = lane >> 4;
    const int hbase = blockIdx.x * 256;

    // ---- issue W DMA for k=0 into buf 0 ----
    #pragma unroll
    for (int i = 0; i < 4; ++i) {
        int row_base = wave * 8 + i * 32; // 8 rows = 1024 B per inst
        dma16(wk + row_base * 64 + lane * 8, &w_s[0][row_base * 64]);
    }

    // ---- early B0 gather: indices straight from global neigh (one-time; latency
    //      overlapped with the whole neigh_s staging phase below) ----
    int4 b0[2][4], b1[2][4];
    {
        #pragma unroll
        for (int nt = 0; nt < 4; ++nt) {
            int n  = wave * 64 + nt * 16 + col;
            int hg = hbase + n;
            int idx = (hg < HH) ? neigh[(size_t)hg * KK] : -1;
            int idxc = (idx < 0) ? HH : idx;                 // row HH = zeros
            const unsigned short* base = xt + (size_t)idxc * 64 + quad * 8;
            b0[0][nt] = *(const int4*)(base);
            b0[1][nt] = *(const int4*)(base + 32);
        }
    }

    // ---- stage neighbor indices (coalesced) ----
    #pragma unroll
    for (int j = 0; j < KK; ++j) {
        int i = j * 256 + tid;                // 6912 = 27*256 exactly
        int hl = i / KK, kx = i - hl * KK;
        int hg = hbase + hl;
        neigh_s[i] = (hg < HH) ? neigh[(size_t)hg * KK + kx] : -1;
    }

    f32x4 acc[8][4];
    #pragma unroll
    for (int mt = 0; mt < 8; ++mt)
        #pragma unroll
        for (int nt = 0; nt < 4; ++nt)
            acc[mt][nt] = (f32x4){0.f, 0.f, 0.f, 0.f};

    __syncthreads();   // neigh_s ready; full drain (DMA k=0 + B0 landed); vmcnt = 0 here

    // ---- B-fragment loader: 8 x 16B UNCONDITIONAL gathers into VGPRs ----
    auto loadB = [&](int kk, int4 (&frag)[2][4]) {
        #pragma unroll
        for (int nt = 0; nt < 4; ++nt) {
            int n = wave * 64 + nt * 16 + col;
            int idx = neigh_s[n * KK + kk];
            int idxc = (idx < 0) ? HH : idx;                 // row HH = zeros
            const unsigned short* base = xt + (size_t)idxc * 64 + quad * 8;
            frag[0][nt] = *(const int4*)(base);
            frag[1][nt] = *(const int4*)(base + 32);
        }
    };

    // ---- one pipeline step: consume `cur` at slice k, prefetch slice k+1 into `nxt` ----
    auto step = [&](int k, int4 (&cur)[2][4], int4 (&nxt)[2][4], bool last) {
        if (!last) {
            const unsigned short* src = wk + (size_t)(k + 1) * (C_OUT * C_IN);
            unsigned short* dst = &w_s[(k + 1) & 1][0];
            #pragma unroll
            for (int i = 0; i < 4; ++i) {
                int row_base = wave * 8 + i * 32;
                dma16(src + row_base * 64 + lane * 8, dst + row_base * 64);
            }
            loadB(k + 1, nxt);   // stays in flight across the barrier below
        }

        // MFMA phase on w_s[k&1] + cur (compiler inserts counted wait for cur here)
        const unsigned short* wp = &w_s[k & 1][0];
        #pragma unroll
        for (int ch = 0; ch < 2; ++ch) {
            const int pc = (ch * 4 + quad) ^ (col & 7);   // physical chunk (XOR swizzle)
            #pragma unroll
            for (int mt = 0; mt < 8; ++mt) {
                s8v a = *(const s8v*)&wp[(mt * 16 + col) * 64 + pc * 8];
                #pragma unroll
                for (int nt = 0; nt < 4; ++nt) {
                    s8v b = __builtin_bit_cast(s8v, cur[ch][nt]);
                    acc[mt][nt] = __builtin_amdgcn_mfma_f32_16x16x32_bf16(a, b, acc[mt][nt], 0, 0, 0);
                }
            }
        }

        if (!last) {
            // retire own 4 W-DMAs + finish LDS reads of this buffer; B gathers stay out
            asm volatile("s_waitcnt vmcnt(8) lgkmcnt(0)" ::: "memory");
            __builtin_amdgcn_s_barrier();
        }
    };

    #pragma unroll 1
    for (int k = 0; k < KK - 1; k += 2) {
        step(k,     b0, b1, false);
        step(k + 1, b1, b0, false);
    }
    step(KK - 1, b0, b1, true);   // k=26 (even -> cur=b0), no prefetch, no barrier

    // ---- epilogue: D row = quad*4+r (o), col = lane&15 (h); relu + fp32 store ----
    #pragma unroll
    for (int mt = 0; mt < 8; ++mt) {
        #pragma unroll
        for (int nt = 0; nt < 4; ++nt) {
            int hg = hbase + wave * 64 + nt * 16 + col;
            if (hg < HH) {
                #pragma unroll
                for (int r = 0; r < 4; ++r) {
                    int o = mt * 16 + quad * 4 + r;
                    float v = acc[mt][nt][r];
                    out[(size_t)o * HH + hg] = v > 0.f ? v : 0.f;
                }
            }
        }
    }
}

extern "C" void kernel_launch(void* const* d_in, const int* in_sizes, int n_in,
                              void* d_out, int out_size, void* d_ws, size_t ws_size,
                              hipStream_t stream) {
    const float* data_in = (const float*)d_in[0];
    const int*   neigh   = (const int*)d_in[1];
    const float* weight  = (const float*)d_in[2];
    float* out = (float*)d_out;

    unsigned short* xt = (unsigned short*)d_ws;            // (H+8)*64 bf16 ~= 12.8 MB
    unsigned short* wk = xt + (size_t)(HH + 8) * 64;       // 27*128*64 bf16 = 442 KB

    prep_kernel<<<TB + WB, 256, 0, stream>>>(data_in, weight, xt, wk);
    conv_main<<<NBLK, 256, 0, stream>>>(xt, wk, neigh, out);
}

// Round 5
// 165.639 us; speedup vs baseline: 1.3556x; 1.0165x over previous
//
#include <hip/hip_runtime.h>
#include <hip/hip_bf16.h>

#define C_IN  64
#define C_OUT 128
#define KK    27
#define HH    100000
#define TB    1563         // transpose blocks = ceil(HH/64)
#define WB    108          // weight-convert blocks (108*2048 = 221184 elems)
#define NBLK  391          // ceil(HH/256)

typedef __attribute__((ext_vector_type(8))) short s8v;    // 8 bf16 (MFMA A/B frag)
typedef __attribute__((ext_vector_type(4))) float f32x4;  // MFMA C/D frag
typedef __attribute__((ext_vector_type(4))) float f4v;    // NT-capable float4
typedef __attribute__((ext_vector_type(4))) int   i4v;    // NT-capable int4

__device__ inline unsigned short f2bf(float f) {
    __hip_bfloat16 h = __float2bfloat16(f);
    return *reinterpret_cast<unsigned short*>(&h);
}

__device__ inline void dma16(const void* g, void* l) {
    __builtin_amdgcn_global_load_lds((const __attribute__((address_space(1))) void*)g,
                                     (__attribute__((address_space(3))) void*)l, 16, 0, 0);
}

// ---- prep: transpose x -> xt (bf16, [h][64] plain, + zeroed shadow row at h=HH),
//      W -> wk (bf16, [k][o][64] XOR-swizzled: phys chunk pj holds logical pj^(o&7)) ----
// Streaming kernel, no reuse: float4 loads (4x fewer instrs), NT cache policy throughout.
__global__ __launch_bounds__(256) void prep_kernel(const float* __restrict__ x,
                                                   const float* __restrict__ w,
                                                   unsigned short* __restrict__ xt,
                                                   unsigned short* __restrict__ wk) {
    const int tid = threadIdx.x;
    if (blockIdx.x < TB) {
        __shared__ __align__(16) unsigned short ts[64 * 72];
        const int hbase = blockIdx.x * 64;
        // 64c x 64h via float4 loads over h (HH % 4 == 0, so a float4 is fully in or out)
        #pragma unroll
        for (int it = 0; it < 4; ++it) {
            int t = it * 256 + tid;           // 0..1023
            int c = t >> 4, hg4 = t & 15;
            int hg = hbase + hg4 * 4;
            f4v v = (f4v){0.f, 0.f, 0.f, 0.f};
            if (hg < HH)
                v = __builtin_nontemporal_load((const f4v*)&x[(size_t)c * HH + hg]);
            ts[(hg4 * 4 + 0) * 72 + c] = f2bf(v.x);
            ts[(hg4 * 4 + 1) * 72 + c] = f2bf(v.y);
            ts[(hg4 * 4 + 2) * 72 + c] = f2bf(v.z);
            ts[(hg4 * 4 + 3) * 72 + c] = f2bf(v.w);
        }
        __syncthreads();
        #pragma unroll
        for (int it = 0; it < 2; ++it) {
            int u = it * 256 + tid;           // 64 rows x 8 chunks of 16B
            int hl = u >> 3, part = u & 7;
            int hg = hbase + hl;
            if (hg < HH)
                __builtin_nontemporal_store(*(const i4v*)&ts[hl * 72 + part * 8],
                                            (i4v*)&xt[(size_t)hg * 64 + part * 8]);
        }
    } else {
        int b = blockIdx.x - TB;
        // zeroed shadow rows HH..HH+7 (gather target for OOB/negative neigh indices)
        if (b == 0 && tid < 64) {
            i4v z = (i4v){0, 0, 0, 0};
            *(i4v*)&xt[(size_t)HH * 64 + tid * 8] = z;
        }
        int base = b * 2048 + tid;
        #pragma unroll
        for (int j = 0; j < 8; ++j) {
            int t = base + j * 256;           // wk index: t = k*8192 + o*64 + jj
            int jj = t & 63, o = (t >> 6) & 127, kx = t >> 13;
            int lc = (jj >> 3) ^ (o & 7);     // logical chunk
            int c  = lc * 8 + (jj & 7);
            wk[t] = f2bf(w[(size_t)o * (C_IN * KK) + c * KK + kx]);
        }
    }
}

// ---------------- main gather-GEMM ----------------
// block 256 thr = 4 waves; tile M=128 (all o) x N=256 h; wave w: h strip [w*64, w*64+64)
// A (weights) async-DMA double-buffered LDS (normal cache policy: wk is hot in L2);
// B (gathered cols) direct global->VGPR, 1-iter prefetch crossing the barrier (R3).
// NEW: out stores + neigh staging are NON-TEMPORAL so the 50MB out stream and 10.8MB
// neigh stream don't evict the 12.8MB xt working set from L2 (32MB aggregate can hold
// xt fully). Gathers keep normal policy (they NEED L2 allocation).
__global__ __launch_bounds__(256, 2) void conv_main(const unsigned short* __restrict__ xt,
                                                    const unsigned short* __restrict__ wk,
                                                    const int* __restrict__ neigh,
                                                    float* __restrict__ out) {
    __shared__ int neigh_s[256 * KK];                            // 27648 B, [h][k]
    __shared__ __align__(16) unsigned short w_s[2][128 * 64];    // 2 x 16 KB, XOR-swizzled rows

    const int tid  = threadIdx.x;
    const int wave = tid >> 6;
    const int lane = tid & 63;
    const int col  = lane & 15;
    const int quad = lane >> 4;
    const int hbase = blockIdx.x * 256;

    // ---- issue W DMA for k=0 into buf 0 ----
    #pragma unroll
    for (int i = 0; i < 4; ++i) {
        int row_base = wave * 8 + i * 32; // 8 rows = 1024 B per inst
        dma16(wk + row_base * 64 + lane * 8, &w_s[0][row_base * 64]);
    }

    // ---- early B0 gather: indices straight from global neigh (one-time; latency
    //      overlapped with the whole neigh_s staging phase below) ----
    int4 b0[2][4], b1[2][4];
    {
        #pragma unroll
        for (int nt = 0; nt < 4; ++nt) {
            int n  = wave * 64 + nt * 16 + col;
            int hg = hbase + n;
            int idx = (hg < HH) ? neigh[(size_t)hg * KK] : -1;
            int idxc = (idx < 0) ? HH : idx;                 // row HH = zeros
            const unsigned short* base = xt + (size_t)idxc * 64 + quad * 8;
            b0[0][nt] = *(const int4*)(base);
            b0[1][nt] = *(const int4*)(base + 32);
        }
    }

    // ---- stage neighbor indices (coalesced, non-temporal: read-once stream) ----
    #pragma unroll
    for (int j = 0; j < KK; ++j) {
        int i = j * 256 + tid;                // 6912 = 27*256 exactly
        int hl = i / KK, kx = i - hl * KK;
        int hg = hbase + hl;
        neigh_s[i] = (hg < HH) ? __builtin_nontemporal_load(&neigh[(size_t)hg * KK + kx]) : -1;
    }

    f32x4 acc[8][4];
    #pragma unroll
    for (int mt = 0; mt < 8; ++mt)
        #pragma unroll
        for (int nt = 0; nt < 4; ++nt)
            acc[mt][nt] = (f32x4){0.f, 0.f, 0.f, 0.f};

    __syncthreads();   // neigh_s ready; full drain (DMA k=0 + B0 landed); vmcnt = 0 here

    // ---- B-fragment loader: 8 x 16B UNCONDITIONAL gathers into VGPRs ----
    auto loadB = [&](int kk, int4 (&frag)[2][4]) {
        #pragma unroll
        for (int nt = 0; nt < 4; ++nt) {
            int n = wave * 64 + nt * 16 + col;
            int idx = neigh_s[n * KK + kk];
            int idxc = (idx < 0) ? HH : idx;                 // row HH = zeros
            const unsigned short* base = xt + (size_t)idxc * 64 + quad * 8;
            frag[0][nt] = *(const int4*)(base);
            frag[1][nt] = *(const int4*)(base + 32);
        }
    };

    // ---- one pipeline step: consume `cur` at slice k, prefetch slice k+1 into `nxt` ----
    auto step = [&](int k, int4 (&cur)[2][4], int4 (&nxt)[2][4], bool last) {
        if (!last) {
            const unsigned short* src = wk + (size_t)(k + 1) * (C_OUT * C_IN);
            unsigned short* dst = &w_s[(k + 1) & 1][0];
            #pragma unroll
            for (int i = 0; i < 4; ++i) {
                int row_base = wave * 8 + i * 32;
                dma16(src + row_base * 64 + lane * 8, dst + row_base * 64);
            }
            loadB(k + 1, nxt);   // stays in flight across the barrier below
        }

        // MFMA phase on w_s[k&1] + cur (compiler inserts counted wait for cur here)
        const unsigned short* wp = &w_s[k & 1][0];
        #pragma unroll
        for (int ch = 0; ch < 2; ++ch) {
            const int pc = (ch * 4 + quad) ^ (col & 7);   // physical chunk (XOR swizzle)
            #pragma unroll
            for (int mt = 0; mt < 8; ++mt) {
                s8v a = *(const s8v*)&wp[(mt * 16 + col) * 64 + pc * 8];
                #pragma unroll
                for (int nt = 0; nt < 4; ++nt) {
                    s8v b = __builtin_bit_cast(s8v, cur[ch][nt]);
                    acc[mt][nt] = __builtin_amdgcn_mfma_f32_16x16x32_bf16(a, b, acc[mt][nt], 0, 0, 0);
                }
            }
        }

        if (!last) {
            // retire own 4 W-DMAs + finish LDS reads of this buffer; B gathers stay out
            asm volatile("s_waitcnt vmcnt(8) lgkmcnt(0)" ::: "memory");
            __builtin_amdgcn_s_barrier();
        }
    };

    #pragma unroll 1
    for (int k = 0; k < KK - 1; k += 2) {
        step(k,     b0, b1, false);
        step(k + 1, b1, b0, false);
    }
    step(KK - 1, b0, b1, true);   // k=26 (even -> cur=b0), no prefetch, no barrier

    // ---- epilogue: D row = quad*4+r (o), col = lane&15 (h); relu + NT fp32 store ----
    #pragma unroll
    for (int mt = 0; mt < 8; ++mt) {
        #pragma unroll
        for (int nt = 0; nt < 4; ++nt) {
            int hg = hbase + wave * 64 + nt * 16 + col;
            if (hg < HH) {
                #pragma unroll
                for (int r = 0; r < 4; ++r) {
                    int o = mt * 16 + quad * 4 + r;
                    float v = acc[mt][nt][r];
                    v = v > 0.f ? v : 0.f;
                    __builtin_nontemporal_store(v, &out[(size_t)o * HH + hg]);
                }
            }
        }
    }
}

extern "C" void kernel_launch(void* const* d_in, const int* in_sizes, int n_in,
                              void* d_out, int out_size, void* d_ws, size_t ws_size,
                              hipStream_t stream) {
    const float* data_in = (const float*)d_in[0];
    const int*   neigh   = (const int*)d_in[1];
    const float* weight  = (const float*)d_in[2];
    float* out = (float*)d_out;

    unsigned short* xt = (unsigned short*)d_ws;            // (H+8)*64 bf16 ~= 12.8 MB
    unsigned short* wk = xt + (size_t)(HH + 8) * 64;       // 27*128*64 bf16 = 442 KB

    prep_kernel<<<TB + WB, 256, 0, stream>>>(data_in, weight, xt, wk);
    conv_main<<<NBLK, 256, 0, stream>>>(xt, wk, neigh, out);
}